// Round 6
// baseline (2607.671 us; speedup 1.0000x reference)
//
#include <hip/hip_runtime.h>
#include <math.h>

#define NB 32768
#define KC 4096
#define DD 512
#define DELTA 6.0f

typedef __attribute__((ext_vector_type(8))) short short8;
typedef __attribute__((ext_vector_type(4))) float facc4;

#define AS1 __attribute__((address_space(1)))
#define AS3 __attribute__((address_space(3)))

__device__ __forceinline__ void gll16(const void* g, void* lds) {
    __builtin_amdgcn_global_load_lds((const AS1 unsigned*)g, (AS3 unsigned*)lds,
                                     16, 0, 0);
}

__device__ __forceinline__ unsigned short f2bf(float f) {
    unsigned u = __float_as_uint(f);
    u += 0x7FFFu + ((u >> 16) & 1u);     // RNE
    return (unsigned short)(u >> 16);
}
__device__ __forceinline__ unsigned ordenc(float f) {
    unsigned u = __float_as_uint(f);
    return (u & 0x80000000u) ? ~u : (u | 0x80000000u);
}

// ---- fp32 -> bf16 convert + tile to [blk][kstep][128 r][64 d], XOR-swizzled ----
// granule g (8 bf16 = 16B) of row r stored at position g ^ (r&7). gll16 then
// stages linearly; the GEMM frag read applies the same XOR (involution).
__global__ __launch_bounds__(256) void tile_bf16_kernel(const float* __restrict__ in,
                                                        unsigned short* __restrict__ out) {
    const size_t t = (size_t)blockIdx.x * 256 + threadIdx.x;
    const int row = (int)(t >> 6);
    const int d0  = (int)(t & 63) << 3;
    const int blk = row >> 7, r = row & 127;
    const int ks  = d0 >> 6,  dw = d0 & 63;
    const int g   = dw >> 3;
    const int dws = ((g ^ (r & 7)) << 3);
    const float4* p = (const float4*)(in + (size_t)row * DD + d0);
    float4 a = p[0], b = p[1];
    unsigned q0 = (unsigned)f2bf(a.x) | ((unsigned)f2bf(a.y) << 16);
    unsigned q1 = (unsigned)f2bf(a.z) | ((unsigned)f2bf(a.w) << 16);
    unsigned q2 = (unsigned)f2bf(b.x) | ((unsigned)f2bf(b.y) << 16);
    unsigned q3 = (unsigned)f2bf(b.z) | ((unsigned)f2bf(b.w) << 16);
    const size_t o = (((size_t)blk * 8 + ks) * 128 + r) * 64 + dws;
    *(uint4*)(out + o) = make_uint4(q0, q1, q2, q3);
}

// ---------------- c_sq[k] = sum_d c[k][d]^2 (fp32) ----------------
__global__ __launch_bounds__(256) void csq_kernel(const float* __restrict__ cent,
                                                  float* __restrict__ csq) {
    const int wid  = threadIdx.x >> 6;
    const int lane = threadIdx.x & 63;
    const int k = (blockIdx.x << 2) + wid;
    const float* row = cent + (size_t)k * DD;
    float s = 0.f;
#pragma unroll
    for (int d = 0; d < DD; d += 64) {
        float v = row[d + lane];
        s = fmaf(v, v, s);
    }
#pragma unroll
    for (int off = 32; off > 0; off >>= 1) s += __shfl_xor(s, off, 64);
    if (lane == 0) csq[k] = s;
}

// ------ single-pass bf16 MFMA GEMM; writes locmin[row][64 half-tiles] ------
// m97 structure, 128x128 tile, BK=64, 32KB LDS. Dispatch map keeps the live
// working set (<=4MB A + 4MB B) L2/L3-resident: mblk=bid>>5, nblk=bid&31;
// hardware XCD round-robin on bid&7 pins nblk%8 per XCD L2.
__global__ __launch_bounds__(256) void gemm_min(
    const unsigned short* __restrict__ xbT, const unsigned short* __restrict__ cbT,
    const float* __restrict__ csq, float* __restrict__ locmin)
{
    __shared__ unsigned short Ab[8192];   // 16KB
    __shared__ unsigned short Bb[8192];   // 16KB

    const int tid = threadIdx.x;
    const int l = tid & 63, w = tid >> 6;
    const int wr = w >> 1, wc = w & 1;

    const int bid = blockIdx.x;
    const int mblk = bid >> 5, nblk = bid & 31;
    const int m0 = mblk * 128, n0 = nblk * 128;

    // staging: wave w copies quarter-tile (4KB) as 4 contiguous 1KB gll16
    const unsigned short* ga = xbT + (size_t)mblk * 8 * 8192 + w * 2048 + l * 8;
    const unsigned short* gb = cbT + (size_t)nblk * 8 * 8192 + w * 2048 + l * 8;

    const int hi = l >> 4, ln = l & 15;

    float rm[4][4];
#pragma unroll
    for (int fr = 0; fr < 4; ++fr)
#pragma unroll
        for (int j = 0; j < 4; ++j) rm[fr][j] = INFINITY;

    facc4 acc[4][4];
#pragma unroll
    for (int fr = 0; fr < 4; ++fr)
#pragma unroll
        for (int fc = 0; fc < 4; ++fc) {
            facc4 z = {0.f, 0.f, 0.f, 0.f};
            acc[fr][fc] = z;
        }

#pragma unroll 1
    for (int ks = 0; ks < 8; ++ks) {
        const unsigned short* sa = ga + (size_t)ks * 8192;
        const unsigned short* sb = gb + (size_t)ks * 8192;
#pragma unroll
        for (int q = 0; q < 4; ++q) {
            gll16(sa + q * 512, &Ab[w * 2048 + q * 512]);
            gll16(sb + q * 512, &Bb[w * 2048 + q * 512]);
        }
        __syncthreads();

        // frag reads: XOR-deswizzle (granule ^ (row&7), row&7 == ln&7)
#pragma unroll
        for (int kk = 0; kk < 2; ++kk) {
            const int ko = ((kk * 4 + hi) ^ (ln & 7)) << 3;
            short8 av[4], bv[4];
#pragma unroll
            for (int fr = 0; fr < 4; ++fr)
                av[fr] = *(const short8*)&Ab[(wr * 64 + fr * 16 + ln) * 64 + ko];
#pragma unroll
            for (int fc = 0; fc < 4; ++fc)
                bv[fc] = *(const short8*)&Bb[(wc * 64 + fc * 16 + ln) * 64 + ko];
#pragma unroll
            for (int fr = 0; fr < 4; ++fr)
#pragma unroll
                for (int fc = 0; fc < 4; ++fc)
                    acc[fr][fc] = __builtin_amdgcn_mfma_f32_16x16x32_bf16(
                        av[fr], bv[fc], acc[fr][fc], 0, 0, 0);
        }
        __syncthreads();
    }

    // epilogue: dist = csq[col] - 2*acc; per-row min over this wave's 64 cols
#pragma unroll
    for (int fc = 0; fc < 4; ++fc) {
        const int col = n0 + wc * 64 + fc * 16 + ln;
        const float q = csq[col];
#pragma unroll
        for (int fr = 0; fr < 4; ++fr)
#pragma unroll
            for (int j = 0; j < 4; ++j)
                rm[fr][j] = fminf(rm[fr][j], fmaf(-2.f, acc[fr][fc][j], q));
    }
#pragma unroll
    for (int off = 1; off < 16; off <<= 1)
#pragma unroll
        for (int fr = 0; fr < 4; ++fr)
#pragma unroll
            for (int j = 0; j < 4; ++j)
                rm[fr][j] = fminf(rm[fr][j], __shfl_xor(rm[fr][j], off, 64));
    if (ln == 0) {
#pragma unroll
        for (int fr = 0; fr < 4; ++fr)
#pragma unroll
            for (int j = 0; j < 4; ++j) {
                const int row = m0 + wr * 64 + fr * 16 + hi * 4 + j;
                locmin[(size_t)row * 64 + nblk * 2 + wc] = rm[fr][j];
            }
    }
}

// ---- thr[row] = min over 64 locmins + DELTA ----
__global__ __launch_bounds__(256) void rowthr_kernel(const float* __restrict__ locmin,
                                                     float* __restrict__ thr) {
    const int row = blockIdx.x * 4 + (threadIdx.x >> 6);
    const int lane = threadIdx.x & 63;
    float v = locmin[(size_t)row * 64 + lane];
#pragma unroll
    for (int off = 32; off > 0; off >>= 1) v = fminf(v, __shfl_xor(v, off, 64));
    if (lane == 0) thr[row] = v + DELTA;
}

// ---- exact fp32 rescue: one wave per row; scan qualifying 64-col half-tiles ----
__global__ __launch_bounds__(256) void rescue_kernel(
    const float* __restrict__ x, const float* __restrict__ cent,
    const float* __restrict__ csq, const float* __restrict__ locmin,
    const float* __restrict__ thr, unsigned long long* __restrict__ keys)
{
    const int row = blockIdx.x * 4 + (threadIdx.x >> 6);
    const int lane = threadIdx.x & 63;
    const int quad = lane >> 4, ln = lane & 15;

    // preload this row of x: lane ln holds elems [ln*32, ln*32+32)
    const float4* xrow4 = (const float4*)(x + (size_t)row * DD);
    float4 xr[8];
#pragma unroll
    for (int i = 0; i < 8; ++i) xr[i] = xrow4[ln * 8 + i];

    const float th = thr[row];
    unsigned long long mask = __ballot(locmin[(size_t)row * 64 + lane] <= th);
    unsigned long long best = ~0ull;

    while (mask) {
        const int ht = (int)__ffsll((long long)mask) - 1;
        mask &= mask - 1;
        // exact fp32 dists for cols [ht*64, ht*64+64), 4 cols at a time
        for (int it = 0; it < 16; ++it) {
            const int col = ht * 64 + it * 4 + quad;
            const float4* c4 = (const float4*)(cent + (size_t)col * DD);
            float s = 0.f;
#pragma unroll
            for (int i = 0; i < 8; ++i) {
                float4 a = xr[i];
                float4 b = c4[ln * 8 + i];
                s = fmaf(a.x, b.x, s);
                s = fmaf(a.y, b.y, s);
                s = fmaf(a.z, b.z, s);
                s = fmaf(a.w, b.w, s);
            }
#pragma unroll
            for (int off = 1; off < 16; off <<= 1) s += __shfl_xor(s, off, 64);
            const float dist = fmaf(-2.f, s, csq[col]);
            unsigned long long key =
                ((unsigned long long)ordenc(dist) << 32) | (unsigned)col;
            best = (key < best) ? key : best;
        }
    }
    // reduce across quads, then one atomic per row
#pragma unroll
    for (int off = 16; off < 64; off <<= 1) {
        unsigned long long o = __shfl_xor(best, off, 64);
        best = (o < best) ? o : best;
    }
    if (lane == 0) atomicMin(&keys[row], best);
}

__global__ __launch_bounds__(256) void finalize_kernel(
        const unsigned long long* __restrict__ keys, int* __restrict__ out) {
    const int i = blockIdx.x * 256 + threadIdx.x;
    out[i] = (int)(keys[i] & 0xFFFFFFFFull);
}

// ---------------- fallback: round-1 fp32 kernel (proven) ----------------
__global__ __launch_bounds__(256) void argmin_fp32_kernel(
        const float* __restrict__ x, const float* __restrict__ cent,
        const float* __restrict__ csq, int* __restrict__ out) {
    __shared__ float xs[16][68];
    __shared__ float cs[16][132];
    const int tid = threadIdx.x;
    const int tx = tid & 15;
    const int ty = tid >> 4;
    const int m0 = blockIdx.x * 64;
    const int srow = tid >> 2;
    const int scol = (tid & 3) << 2;
    const float* xg  = x + (size_t)(m0 + srow) * DD + scol;
    const float* cgA = cent + (size_t)srow * DD + scol;
    const float* cgB = cent + (size_t)(srow + 64) * DD + scol;
    float best[4];
    int bidx[4];
#pragma unroll
    for (int i = 0; i < 4; ++i) { best[i] = INFINITY; bidx[i] = 0; }
    for (int n0 = 0; n0 < KC; n0 += 128) {
        float acc[4][2][4];
#pragma unroll
        for (int i = 0; i < 4; ++i)
#pragma unroll
            for (int h = 0; h < 2; ++h)
#pragma unroll
                for (int j = 0; j < 4; ++j) acc[i][h][j] = 0.f;
        const size_t nOff = (size_t)n0 * DD;
        float4 rx = *(const float4*)(xg);
        float4 rc0 = *(const float4*)(cgA + nOff);
        float4 rc1 = *(const float4*)(cgB + nOff);
        for (int k0 = 0; k0 < DD; k0 += 16) {
            __syncthreads();
            const float* p = (const float*)&rx;
            xs[scol + 0][srow] = p[0]; xs[scol + 1][srow] = p[1];
            xs[scol + 2][srow] = p[2]; xs[scol + 3][srow] = p[3];
            const float* q0 = (const float*)&rc0;
            cs[scol + 0][srow] = q0[0]; cs[scol + 1][srow] = q0[1];
            cs[scol + 2][srow] = q0[2]; cs[scol + 3][srow] = q0[3];
            const float* q1 = (const float*)&rc1;
            cs[scol + 0][srow + 64] = q1[0]; cs[scol + 1][srow + 64] = q1[1];
            cs[scol + 2][srow + 64] = q1[2]; cs[scol + 3][srow + 64] = q1[3];
            __syncthreads();
            if (k0 + 16 < DD) {
                rx  = *(const float4*)(xg + k0 + 16);
                rc0 = *(const float4*)(cgA + nOff + k0 + 16);
                rc1 = *(const float4*)(cgB + nOff + k0 + 16);
            }
#pragma unroll
            for (int dd = 0; dd < 16; ++dd) {
                float4 av  = *(const float4*)&xs[dd][ty << 2];
                float4 bv0 = *(const float4*)&cs[dd][tx << 2];
                float4 bv1 = *(const float4*)&cs[dd][64 + (tx << 2)];
                const float* a  = (const float*)&av;
                const float* b0 = (const float*)&bv0;
                const float* b1 = (const float*)&bv1;
#pragma unroll
                for (int i = 0; i < 4; ++i)
#pragma unroll
                    for (int j = 0; j < 4; ++j) {
                        acc[i][0][j] = fmaf(a[i], b0[j], acc[i][0][j]);
                        acc[i][1][j] = fmaf(a[i], b1[j], acc[i][1][j]);
                    }
            }
        }
        float4 qv0 = *(const float4*)(csq + n0 + (tx << 2));
        float4 qv1 = *(const float4*)(csq + n0 + 64 + (tx << 2));
        const float* q0 = (const float*)&qv0;
        const float* q1 = (const float*)&qv1;
#pragma unroll
        for (int i = 0; i < 4; ++i)
#pragma unroll
            for (int h = 0; h < 2; ++h)
#pragma unroll
                for (int j = 0; j < 4; ++j) {
                    float qq = (h == 0) ? q0[j] : q1[j];
                    float dist = fmaf(-2.f, acc[i][h][j], qq);
                    int kk = n0 + h * 64 + (tx << 2) + j;
                    if (dist < best[i] || (dist == best[i] && kk < bidx[i])) {
                        best[i] = dist; bidx[i] = kk;
                    }
                }
    }
#pragma unroll
    for (int off = 1; off < 16; off <<= 1)
#pragma unroll
        for (int i = 0; i < 4; ++i) {
            float ov = __shfl_xor(best[i], off, 64);
            int oi = __shfl_xor(bidx[i], off, 64);
            if (ov < best[i] || (ov == best[i] && oi < bidx[i])) {
                best[i] = ov; bidx[i] = oi;
            }
        }
    if (tx == 0)
#pragma unroll
        for (int i = 0; i < 4; ++i) out[m0 + (ty << 2) + i] = bidx[i];
}

extern "C" void kernel_launch(void* const* d_in, const int* in_sizes, int n_in,
                              void* d_out, int out_size, void* d_ws, size_t ws_size,
                              hipStream_t stream) {
    const float* x    = (const float*)d_in[0];
    const float* cent = (const float*)d_in[1];
    int* out = (int*)d_out;

    const size_t xb_bytes     = (size_t)NB * DD * 2;   // 32MB
    const size_t cb_bytes     = (size_t)KC * DD * 2;   // 4MB
    const size_t locmin_bytes = (size_t)NB * 64 * 4;   // 8MB
    const size_t thr_bytes    = (size_t)NB * 4;        // 128KB
    const size_t keys_bytes   = (size_t)NB * 8;        // 256KB
    const size_t csq_bytes    = (size_t)KC * 4;        // 16KB
    const size_t need = xb_bytes + cb_bytes + locmin_bytes + thr_bytes +
                        keys_bytes + csq_bytes;

    if (ws_size >= need) {
        char* p = (char*)d_ws;
        unsigned short* xbT = (unsigned short*)p;            p += xb_bytes;
        unsigned short* cbT = (unsigned short*)p;            p += cb_bytes;
        float* locmin = (float*)p;                           p += locmin_bytes;
        float* thr = (float*)p;                              p += thr_bytes;
        unsigned long long* keys = (unsigned long long*)p;   p += keys_bytes;
        float* csq = (float*)p;

        hipMemsetAsync(keys, 0xFF, keys_bytes, stream);
        tile_bf16_kernel<<<NB * DD / 8 / 256, 256, 0, stream>>>(x, xbT);
        tile_bf16_kernel<<<KC * DD / 8 / 256, 256, 0, stream>>>(cent, cbT);
        csq_kernel<<<KC / 4, 256, 0, stream>>>(cent, csq);
        gemm_min<<<(NB / 128) * (KC / 128), 256, 0, stream>>>(xbT, cbT, csq, locmin);
        rowthr_kernel<<<NB / 4, 256, 0, stream>>>(locmin, thr);
        rescue_kernel<<<NB / 4, 256, 0, stream>>>(x, cent, csq, locmin, thr, keys);
        finalize_kernel<<<NB / 256, 256, 0, stream>>>(keys, out);
    } else {
        float* csq = (float*)d_ws;
        csq_kernel<<<KC / 4, 256, 0, stream>>>(cent, csq);
        argmin_fp32_kernel<<<NB / 64, 256, 0, stream>>>(x, cent, csq, out);
    }
}